// Round 1
// baseline (911.525 us; speedup 1.0000x reference)
//
#include <hip/hip_runtime.h>
#include <hip/hip_bf16.h>

typedef __attribute__((ext_vector_type(8))) short short8;
typedef __attribute__((ext_vector_type(4))) short short4v;
typedef __attribute__((ext_vector_type(4))) float f32x4;

__device__ __forceinline__ short f2bs(float x) {
  // RNE float -> bf16 (finite inputs only)
  unsigned u = __float_as_uint(x);
  unsigned r = (u + 0x7fffu + ((u >> 16) & 1u)) >> 16;
  return (short)r;
}

__device__ __forceinline__ float wred_max(float v) {
#pragma unroll
  for (int m = 32; m > 0; m >>= 1) v = fmaxf(v, __shfl_xor(v, m));
  return v;
}
__device__ __forceinline__ float wred_sum(float v) {
#pragma unroll
  for (int m = 32; m > 0; m >>= 1) v += __shfl_xor(v, m);
  return v;
}

__device__ __forceinline__ short8 pack8(const f32x4& a, const f32x4& b) {
  short8 r;
  r[0] = f2bs(a[0]); r[1] = f2bs(a[1]); r[2] = f2bs(a[2]); r[3] = f2bs(a[3]);
  r[4] = f2bs(b[0]); r[5] = f2bs(b[1]); r[6] = f2bs(b[2]); r[7] = f2bs(b[3]);
  return r;
}

// ---------------------------------------------------------------------------
// C = A (fp32, M x 1024) @ W^T (W fp32, 1024 x 1024) + bias
// M = 4096 fixed. Tile 64x64, BK=32, 4 waves.
// MODE 0: store bf16 per-head layout   out[((b*16+h)*1024 + l)*64 + d]
// MODE 2: store bf16 transposed head   out[((b*16+h)*64 + d)*1024 + l]
// MODE 4: store fp32 row-major         out[m*1024 + n]
// ---------------------------------------------------------------------------
template <int MODE>
__global__ __launch_bounds__(256) void gemm_kernel(
    const float* __restrict__ A, const float* __restrict__ W,
    const float* __restrict__ bias, void* __restrict__ outv) {
  constexpr int Kd = 1024;
  const int bm = blockIdx.x >> 4;   // 64 row tiles
  const int bn = blockIdx.x & 15;   // 16 col tiles
  const int m0 = bm * 64, n0 = bn * 64;
  const int tid = threadIdx.x;
  const int lane = tid & 63, w = tid >> 6;
  const int l15 = lane & 15, g = lane >> 4;
  const int wr = w >> 1, wc = w & 1;

  __shared__ short As[64][40];  // stride 40 shorts = 80 B (16B-aligned rows)
  __shared__ short Bs[64][40];

  f32x4 acc[2][2] = {};

  const int srow = tid >> 2;          // 0..63
  const int scol = (tid & 3) * 8;     // 0,8,16,24
  const float* ap = A + (size_t)(m0 + srow) * Kd + scol;
  const float* wp = W + (size_t)(n0 + srow) * Kd + scol;

  for (int kt = 0; kt < Kd / 32; ++kt) {
    f32x4 a0 = *(const f32x4*)(ap);
    f32x4 a1 = *(const f32x4*)(ap + 4);
    f32x4 b0 = *(const f32x4*)(wp);
    f32x4 b1 = *(const f32x4*)(wp + 4);
    ap += 32; wp += 32;
    __syncthreads();  // previous iteration's frag reads done
    *(short8*)&As[srow][scol] = pack8(a0, a1);
    *(short8*)&Bs[srow][scol] = pack8(b0, b1);
    __syncthreads();
    short8 af0 = *(const short8*)&As[wr * 32 + l15][g * 8];
    short8 af1 = *(const short8*)&As[wr * 32 + 16 + l15][g * 8];
    short8 bf0 = *(const short8*)&Bs[wc * 32 + l15][g * 8];
    short8 bf1 = *(const short8*)&Bs[wc * 32 + 16 + l15][g * 8];
    acc[0][0] = __builtin_amdgcn_mfma_f32_16x16x32_bf16(af0, bf0, acc[0][0], 0, 0, 0);
    acc[0][1] = __builtin_amdgcn_mfma_f32_16x16x32_bf16(af0, bf1, acc[0][1], 0, 0, 0);
    acc[1][0] = __builtin_amdgcn_mfma_f32_16x16x32_bf16(af1, bf0, acc[1][0], 0, 0, 0);
    acc[1][1] = __builtin_amdgcn_mfma_f32_16x16x32_bf16(af1, bf1, acc[1][1], 0, 0, 0);
  }

  const float bv0 = bias[n0 + wc * 32 + l15];
  const float bv1 = bias[n0 + wc * 32 + 16 + l15];
#pragma unroll
  for (int t = 0; t < 2; ++t) {
#pragma unroll
    for (int u = 0; u < 2; ++u) {
#pragma unroll
      for (int r = 0; r < 4; ++r) {
        const int row = wr * 32 + t * 16 + g * 4 + r;
        const int c = wc * 32 + u * 16 + l15;
        const int m = m0 + row;
        const float val = acc[t][u][r] + (u ? bv1 : bv0);
        if constexpr (MODE == 0) {
          short* out = (short*)outv;
          const int b = m >> 10, l = m & 1023;
          out[((size_t)(b * 16 + bn) * 1024 + l) * 64 + c] = f2bs(val);
        } else if constexpr (MODE == 2) {
          short* out = (short*)outv;
          const int b = m >> 10, l = m & 1023;
          out[((size_t)(b * 16 + bn) * 64 + c) * 1024 + l] = f2bs(val);
        } else {
          float* out = (float*)outv;
          out[(size_t)m * 1024 + n0 + c] = val;
        }
      }
    }
  }
}

// ---------------------------------------------------------------------------
// Attention: 1 block = (b,h, 16 q-rows). 4 waves / 256 threads.
// LDS (dynamic, 66816 B): fp32 scores S[16][1044]; later aliased as bf16
// P[16][1032] + N[16][1032] for PV MFMA operands.
// ---------------------------------------------------------------------------
__global__ __launch_bounds__(256) void attn_kernel(
    const short* __restrict__ Qw, const short* __restrict__ Kw,
    const short* __restrict__ Vtw, float* __restrict__ posA,
    float* __restrict__ negA, float* __restrict__ po, float* __restrict__ no) {
  constexpr int L = 1024;
  constexpr int SSTR = 1044;   // fp32 row stride
  constexpr int PSTR = 1032;   // bf16 row stride
  extern __shared__ char smem_raw[];
  float (*S)[SSTR] = (float(*)[SSTR])smem_raw;
  short* PN = (short*)smem_raw;  // P rows [0,16*1032), N rows offset 16*1032

  const int idx = blockIdx.x;
  const int bh = idx >> 6;  // b*16+h
  const int qt = idx & 63;
  const int tid = threadIdx.x;
  const int lane = tid & 63;
  const int w = tid >> 6;
  const int l15 = lane & 15;
  const int g = lane >> 4;

  // Q fragments (rows qt*16 + l15, k slices g*8 within each 32)
  const short* qp = Qw + ((size_t)bh * L + qt * 16 + l15) * 64 + g * 8;
  const short8 qf0 = *(const short8*)qp;
  const short8 qf1 = *(const short8*)(qp + 32);

  // ---- QK^T : wave w covers S columns j*64 + w*16 .. +16
  for (int j = 0; j < 16; ++j) {
    const int col0 = j * 64 + w * 16;
    const short* kp = Kw + ((size_t)bh * L + col0 + l15) * 64 + g * 8;
    const short8 kf0 = *(const short8*)kp;
    const short8 kf1 = *(const short8*)(kp + 32);
    f32x4 d = {0.f, 0.f, 0.f, 0.f};
    d = __builtin_amdgcn_mfma_f32_16x16x32_bf16(qf0, kf0, d, 0, 0, 0);
    d = __builtin_amdgcn_mfma_f32_16x16x32_bf16(qf1, kf1, d, 0, 0, 0);
#pragma unroll
    for (int r = 0; r < 4; ++r) S[g * 4 + r][col0 + l15] = d[r] * 0.125f;
  }
  __syncthreads();

  // ---- Phase A: pull scores into registers (wave w owns rows w*4..w*4+3)
  f32x4 v[4][4];
  float rmax[4];
#pragma unroll
  for (int rr = 0; rr < 4; ++rr) {
    const int row = w * 4 + rr;
    const f32x4* Sv = (const f32x4*)&S[row][0];
    float m = -1e30f;
#pragma unroll
    for (int i = 0; i < 4; ++i) {
      v[rr][i] = Sv[lane + 64 * i];
      m = fmaxf(m, fmaxf(fmaxf(v[rr][i][0], v[rr][i][1]),
                         fmaxf(v[rr][i][2], v[rr][i][3])));
    }
    rmax[rr] = wred_max(m);
  }
  __syncthreads();  // all S reads done; LDS may now be overwritten as P/N

  // ---- Phase B: softmax + neg distribution, write fp32 outs + bf16 LDS
#pragma unroll
  for (int rr = 0; rr < 4; ++rr) {
    const int row = w * 4 + rr;
    const float m = rmax[rr];
    float sum = 0.f;
#pragma unroll
    for (int i = 0; i < 4; ++i)
#pragma unroll
      for (int c = 0; c < 4; ++c) {
        v[rr][i][c] = __expf(v[rr][i][c] - m);
        sum += v[rr][i][c];
      }
    sum = wred_sum(sum);
    const float invp = 1.f / sum;

    float t1 = 0.f;
    float* prow = posA + ((size_t)bh * L + qt * 16 + row) * L;
#pragma unroll
    for (int i = 0; i < 4; ++i) {
#pragma unroll
      for (int c = 0; c < 4; ++c) {
        v[rr][i][c] *= invp;
        t1 += 1.f - v[rr][i][c];
      }
      ((f32x4*)prow)[lane + 64 * i] = v[rr][i];
    }
    t1 = wred_sum(t1);
    const float is1 = 1.f / t1;

    f32x4 nr[4];
    float ns = 0.f;
#pragma unroll
    for (int i = 0; i < 4; ++i)
#pragma unroll
      for (int c = 0; c < 4; ++c) {
        const float p = v[rr][i][c];
        const float a = (1.f - p) * is1;
        const float b2 = 1e-6f / (p + 1e-10f);
        nr[i][c] = fminf(a, b2);
        ns += nr[i][c];
      }
    ns = wred_sum(ns);
    const float ins = 1.f / ns;

    float* nrow = negA + ((size_t)bh * L + qt * 16 + row) * L;
    short* pP = PN + row * PSTR;
    short* pN = PN + 16 * PSTR + row * PSTR;
#pragma unroll
    for (int i = 0; i < 4; ++i) {
      f32x4 nv;
#pragma unroll
      for (int c = 0; c < 4; ++c) nv[c] = nr[i][c] * ins;
      ((f32x4*)nrow)[lane + 64 * i] = nv;
      short4v pp, nn;
#pragma unroll
      for (int c = 0; c < 4; ++c) {
        pp[c] = f2bs(v[rr][i][c]);
        nn[c] = f2bs(nv[c]);
      }
      *(short4v*)(pP + 4 * (lane + 64 * i)) = pp;
      *(short4v*)(pN + 4 * (lane + 64 * i)) = nn;
    }
  }
  __syncthreads();

  // ---- PV: wave w owns d-columns w*16..w*16+16
  f32x4 accp = {0.f, 0.f, 0.f, 0.f}, accn = {0.f, 0.f, 0.f, 0.f};
  const short* vbase = Vtw + ((size_t)bh * 64 + w * 16 + l15) * L;
  const short* pPf = PN + l15 * PSTR;
  const short* pNf = PN + 16 * PSTR + l15 * PSTR;
  for (int kt = 0; kt < 32; ++kt) {
    const int k = kt * 32 + g * 8;
    const short8 pf = *(const short8*)(pPf + k);
    const short8 nf = *(const short8*)(pNf + k);
    const short8 vf = *(const short8*)(vbase + k);
    accp = __builtin_amdgcn_mfma_f32_16x16x32_bf16(pf, vf, accp, 0, 0, 0);
    accn = __builtin_amdgcn_mfma_f32_16x16x32_bf16(nf, vf, accn, 0, 0, 0);
  }
  const int b = bh >> 4, h = bh & 15;
#pragma unroll
  for (int r = 0; r < 4; ++r) {
    const size_t off =
        ((size_t)b * L + qt * 16 + g * 4 + r) * 1024 + h * 64 + w * 16 + l15;
    po[off] = accp[r];
    no[off] = accn[r];
  }
}

// ---------------------------------------------------------------------------
extern "C" void kernel_launch(void* const* d_in, const int* in_sizes, int n_in,
                              void* d_out, int out_size, void* d_ws,
                              size_t ws_size, hipStream_t stream) {
  (void)in_sizes; (void)n_in; (void)out_size; (void)ws_size;
  const float* query = (const float*)d_in[0];
  const float* key_  = (const float*)d_in[1];
  const float* value = (const float*)d_in[2];
  const float* Wq = (const float*)d_in[3];
  const float* bq = (const float*)d_in[4];
  const float* Wk = (const float*)d_in[5];
  const float* bk = (const float*)d_in[6];
  const float* Wv = (const float*)d_in[7];
  const float* bv = (const float*)d_in[8];
  const float* Wo = (const float*)d_in[9];
  const float* bo = (const float*)d_in[10];
  float* out = (float*)d_out;

  // workspace layout (58,720,256 bytes total)
  short* Qw = (short*)d_ws;            // 4194304 bf16
  short* Kw = Qw + 4194304;            // 4194304 bf16
  short* Vtw = Kw + 4194304;           // 4194304 bf16 (transposed per head)
  float* po = (float*)(Vtw + 4194304); // 4194304 fp32
  float* no = po + 4194304;            // 4194304 fp32

  gemm_kernel<0><<<1024, 256, 0, stream>>>(query, Wq, bq, (void*)Qw);
  gemm_kernel<0><<<1024, 256, 0, stream>>>(key_, Wk, bk, (void*)Kw);
  gemm_kernel<2><<<1024, 256, 0, stream>>>(value, Wv, bv, (void*)Vtw);

  // d_out layout: pos_output[0, 4194304) | neg_output[4194304, 8388608)
  //               pos_attn [8388608, 75497472) | neg_attn [75497472, ...)
  attn_kernel<<<4096, 256, 66816, stream>>>(Qw, Kw, Vtw, out + 8388608,
                                            out + 75497472, po, no);

  gemm_kernel<4><<<1024, 256, 0, stream>>>(po, Wo, bo, (void*)out);
  gemm_kernel<4><<<1024, 256, 0, stream>>>(no, Wo, bo, (void*)(out + 4194304));
}